// Round 6
// baseline (48.822 us; speedup 1.0000x reference)
//
#include <hip/hip_runtime.h>

#define LQ 2304   // sequence length = 48*48
#define CIN 192
#define EMB 256
#define NH 8
#define HD 32

typedef __attribute__((ext_vector_type(8))) short short8;
typedef __attribute__((ext_vector_type(4))) short short4v;
typedef __attribute__((ext_vector_type(4))) float floatx4;
typedef __attribute__((ext_vector_type(16))) float f32x16;

__device__ __forceinline__ unsigned short f2bf(float f) {
  union { float f; unsigned u; } v; v.f = f;
  unsigned r = v.u + 0x7FFFu + ((v.u >> 16) & 1u);
  return (unsigned short)(r >> 16);
}
__device__ __forceinline__ unsigned cvtpk(float lo, float hi) {
  unsigned r;
  asm("v_cvt_pk_bf16_f32 %0, %1, %2" : "=v"(r) : "v"(lo), "v"(hi));
  return r;
}
// exchange 32-lane halves of (a,b): a' = {a_lo, partner}, b' = {partner, b_hi}
__device__ __forceinline__ void plswap(unsigned& a, unsigned& b, int hi) {
#if __has_builtin(__builtin_amdgcn_permlane32_swap)
  auto r = __builtin_amdgcn_permlane32_swap((int)a, (int)b, false, false);
  a = (unsigned)r[0]; b = (unsigned)r[1];
#else
  unsigned pa = (unsigned)__shfl_xor((int)a, 32);
  unsigned pb = (unsigned)__shfl_xor((int)b, 32);
  unsigned na = hi ? pb : a;
  unsigned nb = hi ? b : pa;
  a = na; b = nb;
#endif
}
__device__ __forceinline__ float xmax(float x, int hi) {
  unsigned a = __float_as_uint(x), b = a;
  plswap(a, b, hi);
  return fmaxf(__uint_as_float(a), __uint_as_float(b));
}
__device__ __forceinline__ float xadd(float x, int hi) {
  unsigned a = __float_as_uint(x), b = a;
  plswap(a, b, hi);
  return __uint_as_float(a) + __uint_as_float(b);
}

// ------- kernel 1: fused transpose + cast + 3-way projection GEMM -------
// z = proj (0:Q from query, 1:K from key, 2:V from key). Block: 32 l-rows, all 256 e.
__global__ __launch_bounds__(256) void k_qkv(
    const float* __restrict__ query, const float* __restrict__ key,
    const float* __restrict__ Wq, const float* __restrict__ Wk, const float* __restrict__ Wv,
    const float* __restrict__ bq, const float* __restrict__ bk, const float* __restrict__ bv,
    unsigned short* Qb, unsigned short* Kb, unsigned short* Vt) {
  __shared__ float tile[64][33];           // [c][l] f32 staging chunk
  __shared__ unsigned short Xs[32][200];   // Xs[l][c], row stride 400B (16B-aligned)

  int proj = blockIdx.z;
  int b = blockIdx.y;
  int l0 = blockIdx.x * 32;
  const float* src  = (proj == 0) ? query : key;
  const float* Wf   = (proj == 0) ? Wq : (proj == 1 ? Wk : Wv);
  const float* bias = (proj == 0) ? bq : (proj == 1 ? bk : bv);
  const float alpha = (proj == 0) ? 0.25505653582177047f : 1.0f; // log2(e)/sqrt(32)

  int tid = threadIdx.x;
  const float* sp = src + (size_t)b * CIN * LQ;

  // stage (C,L) -> Xs[l][c] in three 64-c x 32-l chunks via f32 LDS transpose
  int jl = tid & 31, ic0 = tid >> 5;       // load indexing: 8 c-rows/thread
  int cc = tid & 63, li0 = tid >> 6;       // store indexing: 8 l-cols/thread
  for (int ch = 0; ch < 3; ++ch) {
    int c0 = ch * 64;
    #pragma unroll
    for (int i = ic0; i < 64; i += 8)
      tile[i][jl] = sp[(size_t)(c0 + i) * LQ + l0 + jl];
    __syncthreads();
    #pragma unroll
    for (int li = li0; li < 32; li += 4)
      Xs[li][c0 + cc] = f2bf(tile[cc][li]);
    __syncthreads();
  }

  int lane = tid & 63, w = tid >> 6;
  int g = lane >> 4, r16 = lane & 15;
  int e0 = w * 64;

  floatx4 acc[4][2];
  #pragma unroll
  for (int a = 0; a < 4; ++a)
    #pragma unroll
    for (int ls = 0; ls < 2; ++ls) acc[a][ls] = (floatx4){0.f, 0.f, 0.f, 0.f};

  #pragma unroll
  for (int ks = 0; ks < CIN; ks += 32) {
    short8 wf[4];
    #pragma unroll
    for (int a = 0; a < 4; ++a) {
      const float* wp = Wf + (size_t)(e0 + a * 16 + r16) * CIN + ks + g * 8;
      union { unsigned u[4]; short8 s; } pk;
      pk.u[0] = cvtpk(wp[0], wp[1]);
      pk.u[1] = cvtpk(wp[2], wp[3]);
      pk.u[2] = cvtpk(wp[4], wp[5]);
      pk.u[3] = cvtpk(wp[6], wp[7]);
      wf[a] = pk.s;
    }
    #pragma unroll
    for (int ls = 0; ls < 2; ++ls) {
      short8 xf = *(const short8*)&Xs[ls * 16 + r16][ks + g * 8];
      #pragma unroll
      for (int a = 0; a < 4; ++a)
        acc[a][ls] = __builtin_amdgcn_mfma_f32_16x16x32_bf16(wf[a], xf, acc[a][ls], 0, 0, 0);
    }
  }

  #pragma unroll
  for (int a = 0; a < 4; ++a) {
    int ebase = e0 + a * 16 + g * 4;
    int h = ebase >> 5, d0 = ebase & 31;
    #pragma unroll
    for (int ls = 0; ls < 2; ++ls) {
      int lg = l0 + ls * 16 + r16;
      if (proj < 2) {
        unsigned short* outp = (proj == 0) ? Qb : Kb;
        short4v pk;
        #pragma unroll
        for (int r = 0; r < 4; ++r)
          pk[r] = (short)f2bf((acc[a][ls][r] + bias[ebase + r]) * alpha);
        *(short4v*)(outp + ((size_t)(b * NH + h) * LQ + lg) * HD + d0) = pk;
      } else {
        #pragma unroll
        for (int r = 0; r < 4; ++r)
          Vt[((size_t)(b * NH + h) * HD + d0 + r) * LQ + lg] =
              f2bf(acc[a][ls][r] + bias[ebase + r]);
      }
    }
  }
}

// ------- softmax + PV for one 32q x 64k tile-pair (verified R3 structure) -------
__device__ __forceinline__ void softmax_pv(f32x16& c0, f32x16& c1, f32x16& O,
                                           float& m, float& sum,
                                           const short8* vf, int hi) {
  float mx;
  {
    float a0 = fmaxf(fmaxf(c0[0], c0[8]),  fmaxf(c1[0], c1[8]));
    float a1 = fmaxf(fmaxf(c0[1], c0[9]),  fmaxf(c1[1], c1[9]));
    float a2 = fmaxf(fmaxf(c0[2], c0[10]), fmaxf(c1[2], c1[10]));
    float a3 = fmaxf(fmaxf(c0[3], c0[11]), fmaxf(c1[3], c1[11]));
    float a4 = fmaxf(fmaxf(c0[4], c0[12]), fmaxf(c1[4], c1[12]));
    float a5 = fmaxf(fmaxf(c0[5], c0[13]), fmaxf(c1[5], c1[13]));
    float a6 = fmaxf(fmaxf(c0[6], c0[14]), fmaxf(c1[6], c1[14]));
    float a7 = fmaxf(fmaxf(c0[7], c0[15]), fmaxf(c1[7], c1[15]));
    mx = fmaxf(fmaxf(fmaxf(a0, a1), fmaxf(a2, a3)),
               fmaxf(fmaxf(a4, a5), fmaxf(a6, a7)));
  }
  mx = xmax(mx, hi);

  if (!__all(mx - m <= 8.0f)) {      // deferred-max rescale (THR=8)
    float mn = fmaxf(m, mx);
    float al = exp2f(m - mn);
    sum *= al;
    #pragma unroll
    for (int i = 0; i < 16; ++i) O[i] *= al;
    m = mn;
  }

  #pragma unroll
  for (int i = 0; i < 16; ++i) {
    c0[i] = exp2f(c0[i] - m);
    c1[i] = exp2f(c1[i] - m);
  }
  {
    float a0 = (c0[0] + c0[8])  + (c1[0] + c1[8]);
    float a1 = (c0[1] + c0[9])  + (c1[1] + c1[9]);
    float a2 = (c0[2] + c0[10]) + (c1[2] + c1[10]);
    float a3 = (c0[3] + c0[11]) + (c1[3] + c1[11]);
    float a4 = (c0[4] + c0[12]) + (c1[4] + c1[12]);
    float a5 = (c0[5] + c0[13]) + (c1[5] + c1[13]);
    float a6 = (c0[6] + c0[14]) + (c1[6] + c1[14]);
    float a7 = (c0[7] + c0[15]) + (c1[7] + c1[15]);
    float ts = ((a0 + a1) + (a2 + a3)) + ((a4 + a5) + (a6 + a7));
    sum += xadd(ts, hi);
  }

  union { unsigned u[4]; short8 s; } pA, pB, pC, pD;
  {
    unsigned a = cvtpk(c0[0], c0[1]), b = cvtpk(c0[2], c0[3]);
    unsigned c = cvtpk(c0[4], c0[5]), d = cvtpk(c0[6], c0[7]);
    plswap(a, c, hi); plswap(b, d, hi);
    pA.u[0] = a; pA.u[1] = b; pA.u[2] = c; pA.u[3] = d;
  }
  {
    unsigned a = cvtpk(c0[8], c0[9]),  b = cvtpk(c0[10], c0[11]);
    unsigned c = cvtpk(c0[12], c0[13]), d = cvtpk(c0[14], c0[15]);
    plswap(a, c, hi); plswap(b, d, hi);
    pB.u[0] = a; pB.u[1] = b; pB.u[2] = c; pB.u[3] = d;
  }
  {
    unsigned a = cvtpk(c1[0], c1[1]), b = cvtpk(c1[2], c1[3]);
    unsigned c = cvtpk(c1[4], c1[5]), d = cvtpk(c1[6], c1[7]);
    plswap(a, c, hi); plswap(b, d, hi);
    pC.u[0] = a; pC.u[1] = b; pC.u[2] = c; pC.u[3] = d;
  }
  {
    unsigned a = cvtpk(c1[8], c1[9]),  b = cvtpk(c1[10], c1[11]);
    unsigned c = cvtpk(c1[12], c1[13]), d = cvtpk(c1[14], c1[15]);
    plswap(a, c, hi); plswap(b, d, hi);
    pD.u[0] = a; pD.u[1] = b; pD.u[2] = c; pD.u[3] = d;
  }

  __builtin_amdgcn_s_setprio(1);
  O = __builtin_amdgcn_mfma_f32_32x32x16_bf16(vf[0], pA.s, O, 0, 0, 0);
  O = __builtin_amdgcn_mfma_f32_32x32x16_bf16(vf[1], pB.s, O, 0, 0, 0);
  O = __builtin_amdgcn_mfma_f32_32x32x16_bf16(vf[2], pC.s, O, 0, 0, 0);
  O = __builtin_amdgcn_mfma_f32_32x32x16_bf16(vf[3], pD.s, O, 0, 0, 0);
  __builtin_amdgcn_s_setprio(0);
}

// ------- kernel 2: causal flash attention, 32 q/block, 4-wave k-striping,
//         K-prefetch software pipeline, 4 blocks/CU -------
__global__ __launch_bounds__(256, 4) void k_attn(const unsigned short* __restrict__ Qb,
                                                 const unsigned short* __restrict__ Kb,
                                                 const unsigned short* __restrict__ Vt,
                                                 float* __restrict__ out) {
  __shared__ float Osh[4][32][33];
  __shared__ float Msh[4][32];
  __shared__ float Ssh[4][32];

  int bid = blockIdx.x;               // 0..1151
  int xcd = bid & 7;
  int idx = bid >> 3;                 // 0..143
  int half = idx / 72;
  int j = 71 - (idx - half * 72);     // heavy q-tiles first
  int bh = xcd + 8 * half;
  int q0b = j * 32;

  int w = threadIdx.x >> 6, lane = threadIdx.x & 63;
  int qcol = lane & 31, hi = lane >> 5;
  int qg = q0b + qcol;

  const unsigned short* Qrow = Qb + ((size_t)bh * LQ + qg) * HD + hi * 8;
  short8 qf0 = *(const short8*)(Qrow);
  short8 qf1 = *(const short8*)(Qrow + 16);

  const f32x16 Z16 = {0,0,0,0,0,0,0,0,0,0,0,0,0,0,0,0};
  f32x16 O = Z16;
  float m = -1e30f, sum = 0.f;

  const unsigned short* Kbase = Kb + (size_t)bh * LQ * HD;
  const unsigned short* Vbase = Vt + (size_t)bh * HD * LQ;
  int ntiles = (q0b + 95) >> 6;       // ceil((q0b+32)/64)

  int t = w;
  short8 kf[4];
  if (t < ntiles) {
    const unsigned short* kr = Kbase + (size_t)(t * 64 + qcol) * HD + hi * 8;
    kf[0] = *(const short8*)(kr);
    kf[1] = *(const short8*)(kr + 16);
    kf[2] = *(const short8*)(kr + 32 * HD);
    kf[3] = *(const short8*)(kr + 32 * HD + 16);
  }

  while (t < ntiles) {
    int k0 = t * 64;
    int tn = t + 4;
    int kpre = ((tn < ntiles) ? tn : t) * 64;

    // V for this tile (consumed after softmax — issue first)
    short8 vf[4];
    {
      const unsigned short* vr = Vbase + (size_t)qcol * LQ + k0 + hi * 8;
      vf[0] = *(const short8*)(vr);
      vf[1] = *(const short8*)(vr + 16);
      vf[2] = *(const short8*)(vr + 32);
      vf[3] = *(const short8*)(vr + 48);
    }
    // prefetch next K stripe (consumed next iteration)
    short8 kn[4];
    {
      const unsigned short* kr = Kbase + (size_t)(kpre + qcol) * HD + hi * 8;
      kn[0] = *(const short8*)(kr);
      kn[1] = *(const short8*)(kr + 16);
      kn[2] = *(const short8*)(kr + 32 * HD);
      kn[3] = *(const short8*)(kr + 32 * HD + 16);
    }

    __builtin_amdgcn_s_setprio(1);
    f32x16 c0 = __builtin_amdgcn_mfma_f32_32x32x16_bf16(kf[0], qf0, Z16, 0, 0, 0);
    c0 = __builtin_amdgcn_mfma_f32_32x32x16_bf16(kf[1], qf1, c0, 0, 0, 0);
    f32x16 c1 = __builtin_amdgcn_mfma_f32_32x32x16_bf16(kf[2], qf0, Z16, 0, 0, 0);
    c1 = __builtin_amdgcn_mfma_f32_32x32x16_bf16(kf[3], qf1, c1, 0, 0, 0);
    __builtin_amdgcn_s_setprio(0);

    if (t == ntiles - 1) {            // diagonal tile: causal mask
      #pragma unroll
      for (int i = 0; i < 16; ++i) {
        int kg = k0 + (i & 3) + 8 * (i >> 2) + 4 * hi;
        if (kg > qg)      c0[i] = -1e30f;
        if (kg + 32 > qg) c1[i] = -1e30f;
      }
    }

    softmax_pv(c0, c1, O, m, sum, vf, hi);

    kf[0] = kn[0]; kf[1] = kn[1]; kf[2] = kn[2]; kf[3] = kn[3];
    t = tn;
  }

  // ---- combine the 4 waves' partial (m, sum, O) ----
  #pragma unroll
  for (int i = 0; i < 16; ++i) {
    int d = (i & 3) + 8 * (i >> 2) + 4 * hi;
    Osh[w][d][qcol] = O[i];
  }
  if (hi == 0) { Msh[w][qcol] = m; Ssh[w][qcol] = sum; }
  __syncthreads();

  int tid = threadIdx.x;
  int q = tid & 31, dblk = tid >> 5;
  float m0 = Msh[0][q], m1 = Msh[1][q], m2 = Msh[2][q], m3 = Msh[3][q];
  float ms = fmaxf(fmaxf(m0, m1), fmaxf(m2, m3));
  float a0 = exp2f(m0 - ms), a1 = exp2f(m1 - ms);
  float a2 = exp2f(m2 - ms), a3 = exp2f(m3 - ms);
  float ss = a0 * Ssh[0][q] + a1 * Ssh[1][q] + a2 * Ssh[2][q] + a3 * Ssh[3][q];
  float inv = 1.0f / ss;
  #pragma unroll
  for (int r = 0; r < 4; ++r) {
    int d = dblk * 4 + r;
    float o = a0 * Osh[0][d][q] + a1 * Osh[1][d][q] +
              a2 * Osh[2][d][q] + a3 * Osh[3][d][q];
    out[((size_t)bh * HD + d) * LQ + q0b + q] = o * inv;
  }
}

extern "C" void kernel_launch(void* const* d_in, const int* in_sizes, int n_in,
                              void* d_out, int out_size, void* d_ws, size_t ws_size,
                              hipStream_t stream) {
  const float* query = (const float*)d_in[0];
  const float* key   = (const float*)d_in[1];
  const float* Wq    = (const float*)d_in[2];
  const float* bq    = (const float*)d_in[3];
  const float* Wk    = (const float*)d_in[4];
  const float* bk    = (const float*)d_in[5];
  const float* Wv    = (const float*)d_in[6];
  const float* bv    = (const float*)d_in[7];
  float* out = (float*)d_out;

  unsigned short* Qb = (unsigned short*)d_ws;
  unsigned short* Kb = Qb + 2 * NH * LQ * HD;
  unsigned short* Vt = Kb + 2 * NH * LQ * HD;

  hipLaunchKernelGGL(k_qkv, dim3(72, 2, 3), dim3(256), 0, stream,
                     query, key, Wq, Wk, Wv, bq, bk, bv, Qb, Kb, Vt);
  hipLaunchKernelGGL(k_attn, dim3(1152), dim3(256), 0, stream,
                     Qb, Kb, Vt, out);
}

// Round 7
// 41.370 us; speedup vs baseline: 1.1801x; 1.1801x over previous
//
#include <hip/hip_runtime.h>

#define LQ 2304   // sequence length = 48*48
#define CIN 192
#define EMB 256
#define NH 8
#define HD 32

typedef __attribute__((ext_vector_type(8))) short short8;
typedef __attribute__((ext_vector_type(4))) short short4v;
typedef __attribute__((ext_vector_type(4))) float floatx4;
typedef __attribute__((ext_vector_type(16))) float f32x16;

__device__ __forceinline__ unsigned short f2bf(float f) {
  union { float f; unsigned u; } v; v.f = f;
  unsigned r = v.u + 0x7FFFu + ((v.u >> 16) & 1u);
  return (unsigned short)(r >> 16);
}
__device__ __forceinline__ unsigned cvtpk(float lo, float hi) {
  unsigned r;
  asm("v_cvt_pk_bf16_f32 %0, %1, %2" : "=v"(r) : "v"(lo), "v"(hi));
  return r;
}
// exchange 32-lane halves of (a,b): a' = {a_lo, partner}, b' = {partner, b_hi}
__device__ __forceinline__ void plswap(unsigned& a, unsigned& b, int hi) {
#if __has_builtin(__builtin_amdgcn_permlane32_swap)
  auto r = __builtin_amdgcn_permlane32_swap((int)a, (int)b, false, false);
  a = (unsigned)r[0]; b = (unsigned)r[1];
#else
  unsigned pa = (unsigned)__shfl_xor((int)a, 32);
  unsigned pb = (unsigned)__shfl_xor((int)b, 32);
  unsigned na = hi ? pb : a;
  unsigned nb = hi ? b : pa;
  a = na; b = nb;
#endif
}
__device__ __forceinline__ float xmax(float x, int hi) {
  unsigned a = __float_as_uint(x), b = a;
  plswap(a, b, hi);
  return fmaxf(__uint_as_float(a), __uint_as_float(b));
}
__device__ __forceinline__ float xadd(float x, int hi) {
  unsigned a = __float_as_uint(x), b = a;
  plswap(a, b, hi);
  return __uint_as_float(a) + __uint_as_float(b);
}

// ------- kernel 1: fused transpose + cast + 3-way projection GEMM -------
// z: proj = z%3 (0:Q, 1:K, 2:V), ehalf = z/3. Block: 64 l-rows, 128 e-cols.
__global__ __launch_bounds__(256) void k_qkv(
    const float* __restrict__ query, const float* __restrict__ key,
    const float* __restrict__ Wq, const float* __restrict__ Wk, const float* __restrict__ Wv,
    const float* __restrict__ bq, const float* __restrict__ bk, const float* __restrict__ bv,
    unsigned short* Qb, unsigned short* Kb, unsigned short* Vt) {
  __shared__ float tile[64][65];           // [c][l] f32 staging chunk
  __shared__ unsigned short Xs[64][200];   // Xs[l][c], row stride 400B (16B-aligned)

  int proj = blockIdx.z % 3;
  int ehalf = blockIdx.z / 3;
  int b = blockIdx.y;
  int l0 = blockIdx.x * 64;
  const float* src  = (proj == 0) ? query : key;
  const float* Wf   = (proj == 0) ? Wq : (proj == 1 ? Wk : Wv);
  const float* bias = (proj == 0) ? bq : (proj == 1 ? bk : bv);
  const float alpha = (proj == 0) ? 0.25505653582177047f : 1.0f; // log2(e)/sqrt(32)

  int tid = threadIdx.x;
  const float* sp = src + (size_t)b * CIN * LQ;

  // stage (C,L) -> Xs[l][c] in three 64c x 64l chunks; float4 loads
  int j4 = (tid & 15) * 4, i0 = tid >> 4;  // load: 16 float4/row, 16 rows/pass
  int cc = tid & 63, li0 = tid >> 6;       // store: 64 c-lanes, 16 l/thread
  for (int ch = 0; ch < 3; ++ch) {
    int c0 = ch * 64;
    #pragma unroll
    for (int i = i0; i < 64; i += 16) {
      floatx4 v = *(const floatx4*)(sp + (size_t)(c0 + i) * LQ + l0 + j4);
      tile[i][j4] = v[0]; tile[i][j4 + 1] = v[1];
      tile[i][j4 + 2] = v[2]; tile[i][j4 + 3] = v[3];
    }
    __syncthreads();
    #pragma unroll
    for (int li = li0; li < 64; li += 4)
      Xs[li][c0 + cc] = f2bf(tile[cc][li]);
    __syncthreads();
  }

  int lane = tid & 63, w = tid >> 6;
  int g = lane >> 4, r16 = lane & 15;
  int e0 = ehalf * 128 + w * 32;

  floatx4 acc[2][4];
  #pragma unroll
  for (int a = 0; a < 2; ++a)
    #pragma unroll
    for (int ls = 0; ls < 4; ++ls) acc[a][ls] = (floatx4){0.f, 0.f, 0.f, 0.f};

  #pragma unroll
  for (int ks = 0; ks < CIN; ks += 32) {
    short8 wf[2];
    #pragma unroll
    for (int a = 0; a < 2; ++a) {
      const float* wp = Wf + (size_t)(e0 + a * 16 + r16) * CIN + ks + g * 8;
      floatx4 w0 = *(const floatx4*)(wp);
      floatx4 w1 = *(const floatx4*)(wp + 4);
      union { unsigned u[4]; short8 s; } pk;
      pk.u[0] = cvtpk(w0[0], w0[1]);
      pk.u[1] = cvtpk(w0[2], w0[3]);
      pk.u[2] = cvtpk(w1[0], w1[1]);
      pk.u[3] = cvtpk(w1[2], w1[3]);
      wf[a] = pk.s;
    }
    #pragma unroll
    for (int ls = 0; ls < 4; ++ls) {
      short8 xf = *(const short8*)&Xs[ls * 16 + r16][ks + g * 8];
      #pragma unroll
      for (int a = 0; a < 2; ++a)
        acc[a][ls] = __builtin_amdgcn_mfma_f32_16x16x32_bf16(wf[a], xf, acc[a][ls], 0, 0, 0);
    }
  }

  #pragma unroll
  for (int a = 0; a < 2; ++a) {
    int ebase = e0 + a * 16 + g * 4;
    int h = ebase >> 5, d0 = ebase & 31;
    #pragma unroll
    for (int ls = 0; ls < 4; ++ls) {
      int lg = l0 + ls * 16 + r16;
      if (proj < 2) {
        unsigned short* outp = (proj == 0) ? Qb : Kb;
        short4v pk;
        #pragma unroll
        for (int r = 0; r < 4; ++r)
          pk[r] = (short)f2bf((acc[a][ls][r] + bias[ebase + r]) * alpha);
        *(short4v*)(outp + ((size_t)(b * NH + h) * LQ + lg) * HD + d0) = pk;
      } else {
        #pragma unroll
        for (int r = 0; r < 4; ++r)
          Vt[((size_t)(b * NH + h) * HD + d0 + r) * LQ + lg] =
              f2bf(acc[a][ls][r] + bias[ebase + r]);
      }
    }
  }
}

// ------- softmax + PV for one 32q x 64k tile-pair (verified R3 structure) -------
__device__ __forceinline__ void softmax_pv(f32x16& c0, f32x16& c1, f32x16& O,
                                           float& m, float& sum,
                                           const short8* vf, int hi) {
  float mx;
  {
    float a0 = fmaxf(fmaxf(c0[0], c0[8]),  fmaxf(c1[0], c1[8]));
    float a1 = fmaxf(fmaxf(c0[1], c0[9]),  fmaxf(c1[1], c1[9]));
    float a2 = fmaxf(fmaxf(c0[2], c0[10]), fmaxf(c1[2], c1[10]));
    float a3 = fmaxf(fmaxf(c0[3], c0[11]), fmaxf(c1[3], c1[11]));
    float a4 = fmaxf(fmaxf(c0[4], c0[12]), fmaxf(c1[4], c1[12]));
    float a5 = fmaxf(fmaxf(c0[5], c0[13]), fmaxf(c1[5], c1[13]));
    float a6 = fmaxf(fmaxf(c0[6], c0[14]), fmaxf(c1[6], c1[14]));
    float a7 = fmaxf(fmaxf(c0[7], c0[15]), fmaxf(c1[7], c1[15]));
    mx = fmaxf(fmaxf(fmaxf(a0, a1), fmaxf(a2, a3)),
               fmaxf(fmaxf(a4, a5), fmaxf(a6, a7)));
  }
  mx = xmax(mx, hi);

  if (!__all(mx - m <= 8.0f)) {      // deferred-max rescale (THR=8)
    float mn = fmaxf(m, mx);
    float al = exp2f(m - mn);
    sum *= al;
    #pragma unroll
    for (int i = 0; i < 16; ++i) O[i] *= al;
    m = mn;
  }

  #pragma unroll
  for (int i = 0; i < 16; ++i) {
    c0[i] = exp2f(c0[i] - m);
    c1[i] = exp2f(c1[i] - m);
  }
  {
    float a0 = (c0[0] + c0[8])  + (c1[0] + c1[8]);
    float a1 = (c0[1] + c0[9])  + (c1[1] + c1[9]);
    float a2 = (c0[2] + c0[10]) + (c1[2] + c1[10]);
    float a3 = (c0[3] + c0[11]) + (c1[3] + c1[11]);
    float a4 = (c0[4] + c0[12]) + (c1[4] + c1[12]);
    float a5 = (c0[5] + c0[13]) + (c1[5] + c1[13]);
    float a6 = (c0[6] + c0[14]) + (c1[6] + c1[14]);
    float a7 = (c0[7] + c0[15]) + (c1[7] + c1[15]);
    float ts = ((a0 + a1) + (a2 + a3)) + ((a4 + a5) + (a6 + a7));
    sum += xadd(ts, hi);
  }

  union { unsigned u[4]; short8 s; } pA, pB, pC, pD;
  {
    unsigned a = cvtpk(c0[0], c0[1]), b = cvtpk(c0[2], c0[3]);
    unsigned c = cvtpk(c0[4], c0[5]), d = cvtpk(c0[6], c0[7]);
    plswap(a, c, hi); plswap(b, d, hi);
    pA.u[0] = a; pA.u[1] = b; pA.u[2] = c; pA.u[3] = d;
  }
  {
    unsigned a = cvtpk(c0[8], c0[9]),  b = cvtpk(c0[10], c0[11]);
    unsigned c = cvtpk(c0[12], c0[13]), d = cvtpk(c0[14], c0[15]);
    plswap(a, c, hi); plswap(b, d, hi);
    pB.u[0] = a; pB.u[1] = b; pB.u[2] = c; pB.u[3] = d;
  }
  {
    unsigned a = cvtpk(c1[0], c1[1]), b = cvtpk(c1[2], c1[3]);
    unsigned c = cvtpk(c1[4], c1[5]), d = cvtpk(c1[6], c1[7]);
    plswap(a, c, hi); plswap(b, d, hi);
    pC.u[0] = a; pC.u[1] = b; pC.u[2] = c; pC.u[3] = d;
  }
  {
    unsigned a = cvtpk(c1[8], c1[9]),  b = cvtpk(c1[10], c1[11]);
    unsigned c = cvtpk(c1[12], c1[13]), d = cvtpk(c1[14], c1[15]);
    plswap(a, c, hi); plswap(b, d, hi);
    pD.u[0] = a; pD.u[1] = b; pD.u[2] = c; pD.u[3] = d;
  }

  __builtin_amdgcn_s_setprio(1);
  O = __builtin_amdgcn_mfma_f32_32x32x16_bf16(vf[0], pA.s, O, 0, 0, 0);
  O = __builtin_amdgcn_mfma_f32_32x32x16_bf16(vf[1], pB.s, O, 0, 0, 0);
  O = __builtin_amdgcn_mfma_f32_32x32x16_bf16(vf[2], pC.s, O, 0, 0, 0);
  O = __builtin_amdgcn_mfma_f32_32x32x16_bf16(vf[3], pD.s, O, 0, 0, 0);
  __builtin_amdgcn_s_setprio(0);
}

// ------- kernel 2: causal flash attention, 32 q/block, 4-wave k-striping (R5 exact) -------
__global__ __launch_bounds__(256, 4) void k_attn(const unsigned short* __restrict__ Qb,
                                                 const unsigned short* __restrict__ Kb,
                                                 const unsigned short* __restrict__ Vt,
                                                 float* __restrict__ out) {
  __shared__ float Osh[4][32][33];
  __shared__ float Msh[4][32];
  __shared__ float Ssh[4][32];

  int bid = blockIdx.x;               // 0..1151
  int xcd = bid & 7;
  int idx = bid >> 3;                 // 0..143
  int half = idx / 72;
  int j = 71 - (idx - half * 72);     // heavy q-tiles first
  int bh = xcd + 8 * half;
  int q0b = j * 32;

  int w = threadIdx.x >> 6, lane = threadIdx.x & 63;
  int qcol = lane & 31, hi = lane >> 5;
  int qg = q0b + qcol;

  const unsigned short* Qrow = Qb + ((size_t)bh * LQ + qg) * HD + hi * 8;
  short8 qf0 = *(const short8*)(Qrow);
  short8 qf1 = *(const short8*)(Qrow + 16);

  const f32x16 Z16 = {0,0,0,0,0,0,0,0,0,0,0,0,0,0,0,0};
  f32x16 O = Z16;
  float m = -1e30f, sum = 0.f;

  const unsigned short* Kbase = Kb + (size_t)bh * LQ * HD;
  const unsigned short* Vbase = Vt + (size_t)bh * HD * LQ;
  int ntiles = (q0b + 95) >> 6;       // ceil((q0b+32)/64)

  for (int t = w; t < ntiles; t += 4) {
    int k0 = t * 64;

    short8 kf[4], vf[4];
    {
      const unsigned short* kr = Kbase + (size_t)(k0 + qcol) * HD + hi * 8;
      kf[0] = *(const short8*)(kr);
      kf[1] = *(const short8*)(kr + 16);
      kf[2] = *(const short8*)(kr + 32 * HD);
      kf[3] = *(const short8*)(kr + 32 * HD + 16);
      const unsigned short* vr = Vbase + (size_t)qcol * LQ + k0 + hi * 8;
      vf[0] = *(const short8*)(vr);
      vf[1] = *(const short8*)(vr + 16);
      vf[2] = *(const short8*)(vr + 32);
      vf[3] = *(const short8*)(vr + 48);
    }

    __builtin_amdgcn_s_setprio(1);
    f32x16 c0 = __builtin_amdgcn_mfma_f32_32x32x16_bf16(kf[0], qf0, Z16, 0, 0, 0);
    c0 = __builtin_amdgcn_mfma_f32_32x32x16_bf16(kf[1], qf1, c0, 0, 0, 0);
    f32x16 c1 = __builtin_amdgcn_mfma_f32_32x32x16_bf16(kf[2], qf0, Z16, 0, 0, 0);
    c1 = __builtin_amdgcn_mfma_f32_32x32x16_bf16(kf[3], qf1, c1, 0, 0, 0);
    __builtin_amdgcn_s_setprio(0);

    if (t == ntiles - 1) {            // diagonal tile: causal mask
      #pragma unroll
      for (int i = 0; i < 16; ++i) {
        int kg = k0 + (i & 3) + 8 * (i >> 2) + 4 * hi;
        if (kg > qg)      c0[i] = -1e30f;
        if (kg + 32 > qg) c1[i] = -1e30f;
      }
    }

    softmax_pv(c0, c1, O, m, sum, vf, hi);
  }

  // ---- combine the 4 waves' partial (m, sum, O) ----
  #pragma unroll
  for (int i = 0; i < 16; ++i) {
    int d = (i & 3) + 8 * (i >> 2) + 4 * hi;
    Osh[w][d][qcol] = O[i];
  }
  if (hi == 0) { Msh[w][qcol] = m; Ssh[w][qcol] = sum; }
  __syncthreads();

  int tid = threadIdx.x;
  int q = tid & 31, dblk = tid >> 5;
  float m0 = Msh[0][q], m1 = Msh[1][q], m2 = Msh[2][q], m3 = Msh[3][q];
  float ms = fmaxf(fmaxf(m0, m1), fmaxf(m2, m3));
  float a0 = exp2f(m0 - ms), a1 = exp2f(m1 - ms);
  float a2 = exp2f(m2 - ms), a3 = exp2f(m3 - ms);
  float ss = a0 * Ssh[0][q] + a1 * Ssh[1][q] + a2 * Ssh[2][q] + a3 * Ssh[3][q];
  float inv = 1.0f / ss;
  #pragma unroll
  for (int r = 0; r < 4; ++r) {
    int d = dblk * 4 + r;
    float o = a0 * Osh[0][d][q] + a1 * Osh[1][d][q] +
              a2 * Osh[2][d][q] + a3 * Osh[3][d][q];
    out[((size_t)bh * HD + d) * LQ + q0b + q] = o * inv;
  }
}

extern "C" void kernel_launch(void* const* d_in, const int* in_sizes, int n_in,
                              void* d_out, int out_size, void* d_ws, size_t ws_size,
                              hipStream_t stream) {
  const float* query = (const float*)d_in[0];
  const float* key   = (const float*)d_in[1];
  const float* Wq    = (const float*)d_in[2];
  const float* bq    = (const float*)d_in[3];
  const float* Wk    = (const float*)d_in[4];
  const float* bk    = (const float*)d_in[5];
  const float* Wv    = (const float*)d_in[6];
  const float* bv    = (const float*)d_in[7];
  float* out = (float*)d_out;

  unsigned short* Qb = (unsigned short*)d_ws;
  unsigned short* Kb = Qb + 2 * NH * LQ * HD;
  unsigned short* Vt = Kb + 2 * NH * LQ * HD;

  hipLaunchKernelGGL(k_qkv, dim3(36, 2, 6), dim3(256), 0, stream,
                     query, key, Wq, Wk, Wv, bq, bk, bv, Qb, Kb, Vt);
  hipLaunchKernelGGL(k_attn, dim3(1152), dim3(256), 0, stream,
                     Qb, Kb, Vt, out);
}